// Round 4
// baseline (723.235 us; speedup 1.0000x reference)
//
#include <hip/hip_runtime.h>
#include <math.h>

using u16 = unsigned short;
using u32 = unsigned int;

typedef __attribute__((ext_vector_type(4))) float f32x4;
typedef __attribute__((ext_vector_type(8))) short s16x8;

__device__ __forceinline__ u16 f2bf(float f) {
  union { float f; u32 u; } c; c.f = f;
  u32 u = c.u;
  u += 0x7fffu + ((u >> 16) & 1u);   // round-to-nearest-even
  return (u16)(u >> 16);
}
__device__ __forceinline__ float bf2f(u16 s) {
  union { u32 u; float f; } c; c.u = ((u32)s) << 16;
  return c.f;
}
__device__ __forceinline__ void async16(const void* g, void* l) {
  __builtin_amdgcn_global_load_lds(
      (const __attribute__((address_space(1))) void*)g,
      (__attribute__((address_space(3))) void*)l, 16, 0, 0);
}

// ---------------- LayerNorm: rows x 256 f32 -> bf16, one wave per row ----------------
__global__ __launch_bounds__(256) void ln_kernel(
    const float* __restrict__ x, const float* __restrict__ sc,
    const float* __restrict__ bi, u16* __restrict__ out) {
  const int w = threadIdx.x >> 6, l = threadIdx.x & 63;
  const int row = blockIdx.x * 4 + w;
  const float4 v = ((const float4*)(x + (size_t)row * 256))[l];
  float s  = v.x + v.y + v.z + v.w;
  float s2 = v.x * v.x + v.y * v.y + v.z * v.z + v.w * v.w;
#pragma unroll
  for (int m = 1; m < 64; m <<= 1) {
    s  += __shfl_xor(s,  m, 64);
    s2 += __shfl_xor(s2, m, 64);
  }
  const float mean = s * (1.0f / 256.0f);
  const float var  = s2 * (1.0f / 256.0f) - mean * mean;
  const float rs   = rsqrtf(var + 1e-5f);
  const float4 s4 = ((const float4*)sc)[l];
  const float4 b4 = ((const float4*)bi)[l];
  u16 o0 = f2bf((v.x - mean) * rs * s4.x + b4.x);
  u16 o1 = f2bf((v.y - mean) * rs * s4.y + b4.y);
  u16 o2 = f2bf((v.z - mean) * rs * s4.z + b4.z);
  u16 o3 = f2bf((v.w - mean) * rs * s4.w + b4.w);
  uint2 p; p.x = (u32)o0 | ((u32)o1 << 16); p.y = (u32)o2 | ((u32)o3 << 16);
  *(uint2*)(out + (size_t)row * 256 + l * 4) = p;
}

// ---------------- weight convert f32 [K][N] -> bf16 transposed [N][K] ----------------
__global__ __launch_bounds__(256) void convw_kernel(
    const float* s0, const float* s1, const float* s2, const float* s3,
    const float* s4, const float* s5,
    u16* d0, u16* d1, u16* d2, u16* d3, u16* d4, u16* d5) {
  const float* s; u16* d; int K, N, sh;
  switch (blockIdx.y) {
    case 0: s = s0; d = d0; K = 256; N = 256; sh = 8; break;  // Wq
    case 1: s = s1; d = d1; K = 256; N = 256; sh = 8; break;  // Wgate -> rows 256..511 of WQGT
    case 2: s = s2; d = d2; K = 256; N = 512; sh = 9; break;  // Wkv
    case 3: s = s3; d = d3; K = 256; N = 256; sh = 8; break;  // Wout
    case 4: s = s4; d = d4; K = 256; N = 512; sh = 9; break;  // W1
    default: s = s5; d = d5; K = 512; N = 256; sh = 8; break; // W2
  }
  const int idx = blockIdx.x * 256 + threadIdx.x;
  if (idx >= K * N) return;
  const int k = idx >> sh, n = idx & (N - 1);
  d[(size_t)n * K + k] = f2bf(s[idx]);
}

// ---------------- V transpose: KV v-part -> VT[n][h][c][j] (j contiguous) ----------------
__global__ __launch_bounds__(256) void vtrans_kernel(const u16* __restrict__ KV,
                                                     u16* __restrict__ VT) {
  const int n = blockIdx.x, h = blockIdx.y;
  const int t = threadIdx.x;
  const int j = t >> 2, cg = t & 3;
  union { uint4 v; u16 u[8]; } d;
  d.v = *(const uint4*)(KV + ((size_t)(j * 384 + n)) * 512 + 256 + h * 32 + cg * 8);
  u16* dst = VT + (((size_t)n * 8 + h) * 32 + cg * 8) * 64 + j;
#pragma unroll
  for (int c = 0; c < 8; c++) dst[c * 64] = d.u[c];
}

// ---------------- streaming GEMM: C[M][N] = A[M][K] @ W, BT = W^T [N][K] ----------------
// Tall-skinny specialization: block = 8 waves x 16 rows = 128 rows x 256 cols.
//  - W chunk [256 cols][64 k] lives in 32 KB LDS (chunk-XOR swizzle via pre-swizzled
//    global_load_lds source), K processed in K/64 phases. 32 KB (not 64) to stay clear
//    of the sharedMemPerBlock==65536 edge (prime suspect for the container-fatal launch).
//  - A fragments stream global->VGPR per wave (no A in LDS, no cross-wave A dependency).
//  - 2 barriers per phase gating only the tiny L2-hot W; 16 waves/CU cross-hide them.
// epi: 0 = store bf16; 1 = bf16(relu(acc+bias)); 2 = f32 res+acc*rmask + FUSED LayerNorm
//      (lns/lnb/lnout), grid.x==1 gives each block full 256-col rows; 3 = f32 out+=(acc+bias)*rmask
__global__ __launch_bounds__(512, 4) void gemm_kernel(
    const u16* __restrict__ A, const u16* __restrict__ BT,
    const int K, const int N,
    u16* __restrict__ outb, float* __restrict__ outf,
    const float* __restrict__ bias, const float* __restrict__ res,
    const int* __restrict__ rmask, const int epi,
    const float* __restrict__ lns, const float* __restrict__ lnb,
    u16* __restrict__ lnout) {
  __shared__ u16 Wls[256 * 64];    // 32 KB: [n 0..255][k-local 0..63], swizzled 16B chunks
  const int t = threadIdx.x, w = t >> 6, l = t & 63;
  const int lm = l & 15, lk = l >> 4;

  // XCD-aware bijective swizzle (all grids %8==0): consecutive tiles -> same XCD L2.
  const int nwg = gridDim.x * gridDim.y;
  const int hw = blockIdx.y * gridDim.x + blockIdx.x;
  const int wid = (hw & 7) * (nwg >> 3) + (hw >> 3);
  const int gxm = gridDim.x - 1;                 // gridDim.x in {1,2}
  const int gxsh = (gridDim.x == 2) ? 1 : 0;
  const int nb = (wid & gxm) * 256;              // col base
  const int mb = (wid >> gxsh) * 128;            // row base
  const int KH = K >> 6;                         // phases: 4 (K=256) or 8 (K=512)

  // A: wave w owns rows mb + w*16 .. +15; lane fragment row = lm, k-slot = lk*8
  const u16* arow = A + (size_t)(mb + w * 16 + lm) * K + lk * 8;

  // b-frag LDS read base: row = nt*16 + lm, chunk = (kcl*4+lk) ^ (lm&7)
  const u16* wl = &Wls[lm * 64];
  const int swz = lm & 7;

  f32x4 acc[16] = {};

  for (int kh = 0; kh < KH; ++kh) {
    // issue this phase's A fragments first (they fly during the barrier waits)
    s16x8 av[2];
#pragma unroll
    for (int kcl = 0; kcl < 2; ++kcl)
      av[kcl] = *(const s16x8*)(arow + kh * 64 + kcl * 32);

    if (kh) __syncthreads();   // all waves done reading previous W chunk
    // stage W chunk kh: 2048 16B-slots; slot s = w*64 + i*512 + l (bijective).
    // slot (n,cl) holds global chunk cl ^ (n&7) (involution; read applies same XOR)
#pragma unroll
    for (int i = 0; i < 4; ++i) {
      const int s = w * 64 + i * 512 + l;
      const int n = s >> 3, cl = s & 7;
      const int g = cl ^ (n & 7);
      async16(BT + (size_t)(nb + n) * K + kh * 64 + g * 8,
              &Wls[(w * 64 + i * 512) * 8]);
    }
    __syncthreads();           // implicit vmcnt(0): W chunk (and av) complete

#pragma unroll
    for (int kcl = 0; kcl < 2; ++kcl) {
      const int so = (((kcl << 2) | lk) ^ swz) << 3;
#pragma unroll
      for (int nt = 0; nt < 16; ++nt) {
        const s16x8 bv = *(const s16x8*)(wl + nt * 1024 + so);
        acc[nt] = __builtin_amdgcn_mfma_f32_16x16x32_bf16(av[kcl], bv, acc[nt], 0, 0, 0);
      }
    }
  }

  // epilogue: lane's rows = rowb + r (r 0..3), cols = colb + nt*16
  const int rowb = mb + w * 16 + lk * 4;
  const int colb = nb + lm;
  if (epi == 0) {
#pragma unroll
    for (int nt = 0; nt < 16; ++nt) {
      const int col = colb + nt * 16;
#pragma unroll
      for (int r = 0; r < 4; ++r)
        outb[(size_t)(rowb + r) * N + col] = f2bf(acc[nt][r]);
    }
  } else if (epi == 1) {
#pragma unroll
    for (int nt = 0; nt < 16; ++nt) {
      const int col = colb + nt * 16;
      const float bb = bias[col];
#pragma unroll
      for (int r = 0; r < 4; ++r)
        outb[(size_t)(rowb + r) * N + col] = f2bf(fmaxf(acc[nt][r] + bb, 0.0f));
    }
  } else if (epi == 2) {
    float rm4[4];
#pragma unroll
    for (int r = 0; r < 4; ++r) rm4[r] = (float)rmask[rowb + r];
#pragma unroll
    for (int nt = 0; nt < 16; ++nt) {
      const int col = colb + nt * 16;
#pragma unroll
      for (int r = 0; r < 4; ++r) {
        const size_t idx = (size_t)(rowb + r) * N + col;
        const float x = res[idx] + acc[nt][r] * rm4[r];
        acc[nt][r] = x;
        outf[idx] = x;
      }
    }
    // fused LayerNorm over the full 256-col row (grid.x==1 for this epi):
    // row r lives across the 16 lm-lanes (consecutive within the lk 16-lane group)
    // x 16 nt tiles -> 4-step xor-shuffle reduce stays inside the group.
#pragma unroll
    for (int r = 0; r < 4; ++r) {
      float s = 0.f, s2 = 0.f;
#pragma unroll
      for (int nt = 0; nt < 16; ++nt) { const float v = acc[nt][r]; s += v; s2 += v * v; }
#pragma unroll
      for (int m = 1; m < 16; m <<= 1) {
        s  += __shfl_xor(s,  m, 64);
        s2 += __shfl_xor(s2, m, 64);
      }
      const float mu = s * (1.0f / 256.0f);
      const float var = s2 * (1.0f / 256.0f) - mu * mu;
      const float rs = rsqrtf(var + 1e-5f);
#pragma unroll
      for (int nt = 0; nt < 16; ++nt) {
        const int col = colb + nt * 16;
        const float v = (acc[nt][r] - mu) * rs * lns[col] + lnb[col];
        lnout[(size_t)(rowb + r) * N + col] = f2bf(v);
      }
    }
  } else {
    float rm4[4];
#pragma unroll
    for (int r = 0; r < 4; ++r) rm4[r] = (float)rmask[rowb + r];
#pragma unroll
    for (int nt = 0; nt < 16; ++nt) {
      const int col = colb + nt * 16;
      const float bb = bias[col];
#pragma unroll
      for (int r = 0; r < 4; ++r) {
        const size_t idx = (size_t)(rowb + r) * N + col;
        outf[idx] = outf[idx] + (acc[nt][r] + bb) * rm4[r];
      }
    }
  }
}

// ---------------- attention: softmax over HEADS (axis=-1 of bijnh!), mask cancels ----------------
__global__ __launch_bounds__(256) void attn_kernel(
    const u16* __restrict__ QG, const u16* __restrict__ KV,
    const u16* __restrict__ VT, u16* __restrict__ O) {
  __shared__ u16 P[8][16][72];   // [h][i][j], pad 64->72 to kill read bank conflicts
  const int n = blockIdx.x, ig = blockIdx.y;
  const int t = threadIdx.x, w = t >> 6, l = t & 63;
  const int lm = l & 15, lk = l >> 4;

  const u16* qb = QG + ((size_t)(ig * 16 + lm) * 384 + n) * 512 + lk * 8;
  const u16* kb = KV + ((size_t)(w * 16 + lm) * 384 + n) * 512 + lk * 8;
  const f32x4 zz = {0.f, 0.f, 0.f, 0.f};
  f32x4 acc[8];
#pragma unroll
  for (int h = 0; h < 8; h++) {
    s16x8 af = *(const s16x8*)(qb + h * 32);
    s16x8 bf = *(const s16x8*)(kb + h * 32);
    acc[h] = __builtin_amdgcn_mfma_f32_16x16x32_bf16(af, bf, zz, 0, 0, 0);
  }
#pragma unroll
  for (int r = 0; r < 4; r++) {
    float mx = acc[0][r];
#pragma unroll
    for (int h = 1; h < 8; h++) mx = fmaxf(mx, acc[h][r]);
    float e[8], s = 0.f;
#pragma unroll
    for (int h = 0; h < 8; h++) { e[h] = __expf(acc[h][r] - mx); s += e[h]; }
    const float inv = 1.0f / s;
#pragma unroll
    for (int h = 0; h < 8; h++) P[h][lk * 4 + r][w * 16 + lm] = f2bf(e[h] * inv);
  }
  __syncthreads();

  const u16* vb = VT + ((size_t)n * 8) * 2048;   // [h][c 32][j 64]
#pragma unroll
  for (int hh = 0; hh < 2; hh++) {
    const int h = w * 2 + hh;
#pragma unroll
    for (int nt = 0; nt < 2; nt++) {
      f32x4 o = zz;
#pragma unroll
      for (int ks = 0; ks < 2; ks++) {
        s16x8 af = *(const s16x8*)&P[h][lm][ks * 32 + lk * 8];
        s16x8 bf = *(const s16x8*)(vb + (size_t)h * 2048 + (nt * 16 + lm) * 64 + ks * 32 + lk * 8);
        o = __builtin_amdgcn_mfma_f32_16x16x32_bf16(af, bf, o, 0, 0, 0);
      }
#pragma unroll
      for (int r = 0; r < 4; r++) {
        const int i = ig * 16 + lk * 4 + r;
        const int col = h * 32 + nt * 16 + lm;
        const size_t orow = (size_t)i * 384 + n;
        const float g = bf2f(QG[orow * 512 + 256 + col]);
        const float val = o[r] / (1.0f + __expf(-g));   // out * sigmoid(gate)
        O[orow * 256 + col] = f2bf(val);
      }
    }
  }
}

extern "C" void kernel_launch(void* const* d_in, const int* in_sizes, int n_in,
                              void* d_out, int out_size, void* d_ws, size_t ws_size,
                              hipStream_t stream) {
  (void)in_sizes; (void)n_in; (void)out_size; (void)ws_size;
  const float* embed  = (const float*)d_in[0];
  const float* memory = (const float*)d_in[1];
  const int*   rmask  = (const int*)d_in[2];
  // d_in[3] memory_mask: provably no effect (softmax over h cancels the bias)
  const float* lnqs = (const float*)d_in[4];
  const float* lnqb = (const float*)d_in[5];
  const float* lnks = (const float*)d_in[6];
  const float* lnkb = (const float*)d_in[7];
  const float* Wq   = (const float*)d_in[8];
  const float* Wkv  = (const float*)d_in[9];
  const float* Wg   = (const float*)d_in[10];
  const float* Wo   = (const float*)d_in[11];
  const float* lnfs = (const float*)d_in[12];
  const float* lnfb = (const float*)d_in[13];
  const float* W1   = (const float*)d_in[14];
  const float* b1   = (const float*)d_in[15];
  const float* W2   = (const float*)d_in[16];
  const float* b2   = (const float*)d_in[17];
  float* out = (float*)d_out;
  char* ws = (char*)d_ws;

  // workspace layout (peak 240.3 MB, with aliasing)
  u16* qe   = (u16*)(ws + 0);              // 98304x256 bf16
  u16* km   = (u16*)(ws + 50331648);       // 24576x256 bf16
  u16* VT   = km;                          // aliases km (dead after KV GEMM): 384*8*32*64
  u16* QG   = (u16*)(ws + 62914560);       // 98304x512 bf16 (q | gate)
  u16* h1   = QG;                          // aliases QG (dead after attention)
  u16* KV   = (u16*)(ws + 163577856);      // 24576x512 bf16 (k | v)
  u16* O    = (u16*)(ws + 188743680);      // 98304x256 bf16 gated attn out
  u16* WQGT = (u16*)(ws + 239075328);      // [512][256]
  u16* WKVT = WQGT + 131072;               // [512][256]
  u16* WOUTT= WKVT + 131072;               // [256][256]
  u16* W1T  = WOUTT + 65536;               // [512][256]
  u16* W2T  = W1T + 131072;                // [256][512]
  u16* lnx  = qe;                          // aliases qe (dead after QG GEMM)

  convw_kernel<<<dim3(512, 6), 256, 0, stream>>>(Wq, Wg, Wkv, Wo, W1, W2,
      WQGT, WQGT + 65536, WKVT, WOUTT, W1T, W2T);
  ln_kernel<<<24576, 256, 0, stream>>>(embed, lnqs, lnqb, qe);
  ln_kernel<<<6144, 256, 0, stream>>>(memory, lnks, lnkb, km);
  // QG = qe @ [Wq|Wgate]
  gemm_kernel<<<dim3(2, 768), 512, 0, stream>>>(qe, WQGT, 256, 512, QG, nullptr,
      nullptr, nullptr, nullptr, 0, nullptr, nullptr, nullptr);
  // KV = km @ Wkv
  gemm_kernel<<<dim3(2, 192), 512, 0, stream>>>(km, WKVT, 256, 512, KV, nullptr,
      nullptr, nullptr, nullptr, 0, nullptr, nullptr, nullptr);
  vtrans_kernel<<<dim3(384, 8), 256, 0, stream>>>(KV, VT);
  attn_kernel<<<dim3(384, 16), 256, 0, stream>>>(QG, KV, VT, O);
  // out = embed + (O @ Wout)*rmask, plus FUSED LayerNorm -> lnx (bf16)
  gemm_kernel<<<dim3(1, 768), 512, 0, stream>>>(O, WOUTT, 256, 256, nullptr, out,
      nullptr, embed, rmask, 2, lnfs, lnfb, lnx);
  // h1 = relu(lnx @ W1 + b1)
  gemm_kernel<<<dim3(2, 768), 512, 0, stream>>>(lnx, W1T, 256, 512, h1, nullptr,
      b1, nullptr, nullptr, 1, nullptr, nullptr, nullptr);
  // out += (h1 @ W2 + b2)*rmask
  gemm_kernel<<<dim3(1, 768), 512, 0, stream>>>(h1, W2T, 512, 256, nullptr, out,
      b2, nullptr, rmask, 3, nullptr, nullptr, nullptr);
}

// Round 6
// 613.716 us; speedup vs baseline: 1.1785x; 1.1785x over previous
//
#include <hip/hip_runtime.h>
#include <math.h>

using u16 = unsigned short;
using u32 = unsigned int;

typedef __attribute__((ext_vector_type(4))) float f32x4;
typedef __attribute__((ext_vector_type(8))) short s16x8;

__device__ __forceinline__ u16 f2bf(float f) {
  union { float f; u32 u; } c; c.f = f;
  u32 u = c.u;
  u += 0x7fffu + ((u >> 16) & 1u);   // round-to-nearest-even
  return (u16)(u >> 16);
}
__device__ __forceinline__ float bf2f(u16 s) {
  union { u32 u; float f; } c; c.u = ((u32)s) << 16;
  return c.f;
}
__device__ __forceinline__ void async16(const void* g, void* l) {
  __builtin_amdgcn_global_load_lds(
      (const __attribute__((address_space(1))) void*)g,
      (__attribute__((address_space(3))) void*)l, 16, 0, 0);
}

// ---------------- LayerNorm: rows x 256 f32 -> bf16, one wave per row ----------------
__global__ __launch_bounds__(256) void ln_kernel(
    const float* __restrict__ x, const float* __restrict__ sc,
    const float* __restrict__ bi, u16* __restrict__ out) {
  const int w = threadIdx.x >> 6, l = threadIdx.x & 63;
  const int row = blockIdx.x * 4 + w;
  const float4 v = ((const float4*)(x + (size_t)row * 256))[l];
  float s  = v.x + v.y + v.z + v.w;
  float s2 = v.x * v.x + v.y * v.y + v.z * v.z + v.w * v.w;
#pragma unroll
  for (int m = 1; m < 64; m <<= 1) {
    s  += __shfl_xor(s,  m, 64);
    s2 += __shfl_xor(s2, m, 64);
  }
  const float mean = s * (1.0f / 256.0f);
  const float var  = s2 * (1.0f / 256.0f) - mean * mean;
  const float rs   = rsqrtf(var + 1e-5f);
  const float4 s4 = ((const float4*)sc)[l];
  const float4 b4 = ((const float4*)bi)[l];
  u16 o0 = f2bf((v.x - mean) * rs * s4.x + b4.x);
  u16 o1 = f2bf((v.y - mean) * rs * s4.y + b4.y);
  u16 o2 = f2bf((v.z - mean) * rs * s4.z + b4.z);
  u16 o3 = f2bf((v.w - mean) * rs * s4.w + b4.w);
  uint2 p; p.x = (u32)o0 | ((u32)o1 << 16); p.y = (u32)o2 | ((u32)o3 << 16);
  *(uint2*)(out + (size_t)row * 256 + l * 4) = p;
}

// ---------------- weight convert f32 [K][N] -> bf16 transposed [N][K] ----------------
__global__ __launch_bounds__(256) void convw_kernel(
    const float* s0, const float* s1, const float* s2, const float* s3,
    const float* s4, const float* s5,
    u16* d0, u16* d1, u16* d2, u16* d3, u16* d4, u16* d5) {
  const float* s; u16* d; int K, N, sh;
  switch (blockIdx.y) {
    case 0: s = s0; d = d0; K = 256; N = 256; sh = 8; break;  // Wq
    case 1: s = s1; d = d1; K = 256; N = 256; sh = 8; break;  // Wgate -> rows 256..511 of WQGT
    case 2: s = s2; d = d2; K = 256; N = 512; sh = 9; break;  // Wkv
    case 3: s = s3; d = d3; K = 256; N = 256; sh = 8; break;  // Wout
    case 4: s = s4; d = d4; K = 256; N = 512; sh = 9; break;  // W1
    default: s = s5; d = d5; K = 512; N = 256; sh = 8; break; // W2
  }
  const int idx = blockIdx.x * 256 + threadIdx.x;
  if (idx >= K * N) return;
  const int k = idx >> sh, n = idx & (N - 1);
  d[(size_t)n * K + k] = f2bf(s[idx]);
}

// ---------------- V transpose: KV v-part -> VT[n][h][c][j] (j contiguous) ----------------
__global__ __launch_bounds__(256) void vtrans_kernel(const u16* __restrict__ KV,
                                                     u16* __restrict__ VT) {
  const int n = blockIdx.x, h = blockIdx.y;
  const int t = threadIdx.x;
  const int j = t >> 2, cg = t & 3;
  union { uint4 v; u16 u[8]; } d;
  d.v = *(const uint4*)(KV + ((size_t)(j * 384 + n)) * 512 + 256 + h * 32 + cg * 8);
  u16* dst = VT + (((size_t)n * 8 + h) * 32 + cg * 8) * 64 + j;
#pragma unroll
  for (int c = 0; c < 8; c++) dst[c * 64] = d.u[c];
}

// ---------------- streaming GEMM: C[M][N] = A[M][K] @ W, BT = W^T [N][K] ----------------
// Tall-skinny specialization: block = 8 waves x 16 rows = 128 rows x 256 cols.
//  - W chunk [256 cols][64 k] lives in 32 KB LDS (chunk-XOR swizzle via pre-swizzled
//    global_load_lds source), K processed in K/64 phases.
//  - A fragments stream global->VGPR per wave (no A in LDS, no cross-wave A dependency).
//  - 2 barriers per phase gating only the tiny L2-hot W.
// epi: 0 = store bf16; 1 = bf16(relu(acc+bias)); 2 = f32 res+acc*rmask + FUSED LayerNorm
//      (lns/lnb/lnout), STREAMING: acc consumed in one pass (sum/sumsq on the fly), LN
//      pass re-reads the block's own L2-hot outf — keeps epilogue liveness at K-loop
//      level (R4 kept all 64 acc floats live through a 2nd pass -> ~157 MB scratch
//      spill traffic, WRITE_SIZE 310 MB vs 151 ideal, dispatch 184 us);
// 3 = f32 out+=(acc+bias)*rmask
__global__ __launch_bounds__(512, 4) void gemm_kernel(
    const u16* __restrict__ A, const u16* __restrict__ BT,
    const int K, const int N,
    u16* __restrict__ outb, float* __restrict__ outf,
    const float* __restrict__ bias, const float* __restrict__ res,
    const int* __restrict__ rmask, const int epi,
    const float* __restrict__ lns, const float* __restrict__ lnb,
    u16* __restrict__ lnout) {
  __shared__ u16 Wls[256 * 64];    // 32 KB: [n 0..255][k-local 0..63], swizzled 16B chunks
  const int t = threadIdx.x, w = t >> 6, l = t & 63;
  const int lm = l & 15, lk = l >> 4;

  // XCD-aware bijective swizzle (all grids %8==0): consecutive tiles -> same XCD L2.
  const int nwg = gridDim.x * gridDim.y;
  const int hw = blockIdx.y * gridDim.x + blockIdx.x;
  const int wid = (hw & 7) * (nwg >> 3) + (hw >> 3);
  const int gxm = gridDim.x - 1;                 // gridDim.x in {1,2}
  const int gxsh = (gridDim.x == 2) ? 1 : 0;
  const int nb = (wid & gxm) * 256;              // col base
  const int mb = (wid >> gxsh) * 128;            // row base
  const int KH = K >> 6;                         // phases: 4 (K=256) or 8 (K=512)

  // A: wave w owns rows mb + w*16 .. +15; lane fragment row = lm, k-slot = lk*8
  const u16* arow = A + (size_t)(mb + w * 16 + lm) * K + lk * 8;

  // b-frag LDS read base: row = nt*16 + lm, chunk = (kcl*4+lk) ^ (lm&7)
  const u16* wl = &Wls[lm * 64];
  const int swz = lm & 7;

  f32x4 acc[16] = {};

  for (int kh = 0; kh < KH; ++kh) {
    // issue this phase's A fragments first (they fly during the barrier waits)
    s16x8 av[2];
#pragma unroll
    for (int kcl = 0; kcl < 2; ++kcl)
      av[kcl] = *(const s16x8*)(arow + kh * 64 + kcl * 32);

    if (kh) __syncthreads();   // all waves done reading previous W chunk
    // stage W chunk kh: 2048 16B-slots; slot s = w*64 + i*512 + l (bijective).
    // slot (n,cl) holds global chunk cl ^ (n&7) (involution; read applies same XOR)
#pragma unroll
    for (int i = 0; i < 4; ++i) {
      const int s = w * 64 + i * 512 + l;
      const int n = s >> 3, cl = s & 7;
      const int g = cl ^ (n & 7);
      async16(BT + (size_t)(nb + n) * K + kh * 64 + g * 8,
              &Wls[(w * 64 + i * 512) * 8]);
    }
    __syncthreads();           // implicit vmcnt(0): W chunk (and av) complete

#pragma unroll
    for (int kcl = 0; kcl < 2; ++kcl) {
      const int so = (((kcl << 2) | lk) ^ swz) << 3;
#pragma unroll
      for (int nt = 0; nt < 16; ++nt) {
        const s16x8 bv = *(const s16x8*)(wl + nt * 1024 + so);
        acc[nt] = __builtin_amdgcn_mfma_f32_16x16x32_bf16(av[kcl], bv, acc[nt], 0, 0, 0);
      }
    }
  }

  // epilogue: lane's rows = rowb + r (r 0..3), cols = colb + nt*16
  const int rowb = mb + w * 16 + lk * 4;
  const int colb = nb + lm;
  if (epi == 0) {
#pragma unroll
    for (int nt = 0; nt < 16; ++nt) {
      const int col = colb + nt * 16;
#pragma unroll
      for (int r = 0; r < 4; ++r)
        outb[(size_t)(rowb + r) * N + col] = f2bf(acc[nt][r]);
    }
  } else if (epi == 1) {
#pragma unroll
    for (int nt = 0; nt < 16; ++nt) {
      const int col = colb + nt * 16;
      const float bb = bias[col];
#pragma unroll
      for (int r = 0; r < 4; ++r)
        outb[(size_t)(rowb + r) * N + col] = f2bf(fmaxf(acc[nt][r] + bb, 0.0f));
    }
  } else if (epi == 2) {
    float rm4[4];
#pragma unroll
    for (int r = 0; r < 4; ++r) rm4[r] = (float)rmask[rowb + r];
    // pass 1: consume acc streaming; write outf; accumulate per-row sum/sumsq
    float s[4] = {0.f, 0.f, 0.f, 0.f}, s2[4] = {0.f, 0.f, 0.f, 0.f};
#pragma unroll
    for (int nt = 0; nt < 16; ++nt) {
      const int col = colb + nt * 16;
#pragma unroll
      for (int r = 0; r < 4; ++r) {
        const size_t idx = (size_t)(rowb + r) * N + col;
        const float x = res[idx] + acc[nt][r] * rm4[r];
        outf[idx] = x;
        s[r] += x;
        s2[r] += x * x;
      }
    }
    // reduce within the 16-lane lm-group (each lk-group's lanes hold the same rows)
    float mu[4], rs4[4];
#pragma unroll
    for (int r = 0; r < 4; ++r) {
#pragma unroll
      for (int m = 1; m < 16; m <<= 1) {
        s[r]  += __shfl_xor(s[r],  m, 64);
        s2[r] += __shfl_xor(s2[r], m, 64);
      }
      mu[r] = s[r] * (1.0f / 256.0f);
      const float var = s2[r] * (1.0f / 256.0f) - mu[r] * mu[r];
      rs4[r] = rsqrtf(var + 1e-5f);
    }
    // pass 2: re-read the block's own (L2-hot) outf, write bf16 LN output
#pragma unroll
    for (int nt = 0; nt < 16; ++nt) {
      const int col = colb + nt * 16;
      const float ls = lns[col], lb = lnb[col];
#pragma unroll
      for (int r = 0; r < 4; ++r) {
        const size_t idx = (size_t)(rowb + r) * N + col;
        const float x = outf[idx];
        lnout[(size_t)(rowb + r) * N + col] = f2bf((x - mu[r]) * rs4[r] * ls + lb);
      }
    }
  } else {
    float rm4[4];
#pragma unroll
    for (int r = 0; r < 4; ++r) rm4[r] = (float)rmask[rowb + r];
#pragma unroll
    for (int nt = 0; nt < 16; ++nt) {
      const int col = colb + nt * 16;
      const float bb = bias[col];
#pragma unroll
      for (int r = 0; r < 4; ++r) {
        const size_t idx = (size_t)(rowb + r) * N + col;
        outf[idx] = outf[idx] + (acc[nt][r] + bb) * rm4[r];
      }
    }
  }
}

// ---------------- attention: softmax over HEADS (axis=-1 of bijnh!), mask cancels ----------------
__global__ __launch_bounds__(256) void attn_kernel(
    const u16* __restrict__ QG, const u16* __restrict__ KV,
    const u16* __restrict__ VT, u16* __restrict__ O) {
  __shared__ u16 P[8][16][72];   // [h][i][j], pad 64->72 to kill read bank conflicts
  const int n = blockIdx.x, ig = blockIdx.y;
  const int t = threadIdx.x, w = t >> 6, l = t & 63;
  const int lm = l & 15, lk = l >> 4;

  const u16* qb = QG + ((size_t)(ig * 16 + lm) * 384 + n) * 512 + lk * 8;
  const u16* kb = KV + ((size_t)(w * 16 + lm) * 384 + n) * 512 + lk * 8;
  const f32x4 zz = {0.f, 0.f, 0.f, 0.f};
  f32x4 acc[8];
#pragma unroll
  for (int h = 0; h < 8; h++) {
    s16x8 af = *(const s16x8*)(qb + h * 32);
    s16x8 bf = *(const s16x8*)(kb + h * 32);
    acc[h] = __builtin_amdgcn_mfma_f32_16x16x32_bf16(af, bf, zz, 0, 0, 0);
  }
#pragma unroll
  for (int r = 0; r < 4; r++) {
    float mx = acc[0][r];
#pragma unroll
    for (int h = 1; h < 8; h++) mx = fmaxf(mx, acc[h][r]);
    float e[8], s = 0.f;
#pragma unroll
    for (int h = 0; h < 8; h++) { e[h] = __expf(acc[h][r] - mx); s += e[h]; }
    const float inv = 1.0f / s;
#pragma unroll
    for (int h = 0; h < 8; h++) P[h][lk * 4 + r][w * 16 + lm] = f2bf(e[h] * inv);
  }
  __syncthreads();

  const u16* vb = VT + ((size_t)n * 8) * 2048;   // [h][c 32][j 64]
#pragma unroll
  for (int hh = 0; hh < 2; hh++) {
    const int h = w * 2 + hh;
#pragma unroll
    for (int nt = 0; nt < 2; nt++) {
      f32x4 o = zz;
#pragma unroll
      for (int ks = 0; ks < 2; ks++) {
        s16x8 af = *(const s16x8*)&P[h][lm][ks * 32 + lk * 8];
        s16x8 bf = *(const s16x8*)(vb + (size_t)h * 2048 + (nt * 16 + lm) * 64 + ks * 32 + lk * 8);
        o = __builtin_amdgcn_mfma_f32_16x16x32_bf16(af, bf, o, 0, 0, 0);
      }
#pragma unroll
      for (int r = 0; r < 4; r++) {
        const int i = ig * 16 + lk * 4 + r;
        const int col = h * 32 + nt * 16 + lm;
        const size_t orow = (size_t)i * 384 + n;
        const float g = bf2f(QG[orow * 512 + 256 + col]);
        const float val = o[r] / (1.0f + __expf(-g));   // out * sigmoid(gate)
        O[orow * 256 + col] = f2bf(val);
      }
    }
  }
}

extern "C" void kernel_launch(void* const* d_in, const int* in_sizes, int n_in,
                              void* d_out, int out_size, void* d_ws, size_t ws_size,
                              hipStream_t stream) {
  (void)in_sizes; (void)n_in; (void)out_size; (void)ws_size;
  const float* embed  = (const float*)d_in[0];
  const float* memory = (const float*)d_in[1];
  const int*   rmask  = (const int*)d_in[2];
  // d_in[3] memory_mask: provably no effect (softmax over h cancels the bias)
  const float* lnqs = (const float*)d_in[4];
  const float* lnqb = (const float*)d_in[5];
  const float* lnks = (const float*)d_in[6];
  const float* lnkb = (const float*)d_in[7];
  const float* Wq   = (const float*)d_in[8];
  const float* Wkv  = (const float*)d_in[9];
  const float* Wg   = (const float*)d_in[10];
  const float* Wo   = (const float*)d_in[11];
  const float* lnfs = (const float*)d_in[12];
  const float* lnfb = (const float*)d_in[13];
  const float* W1   = (const float*)d_in[14];
  const float* b1   = (const float*)d_in[15];
  const float* W2   = (const float*)d_in[16];
  const float* b2   = (const float*)d_in[17];
  float* out = (float*)d_out;
  char* ws = (char*)d_ws;

  // workspace layout (peak 240.3 MB, with aliasing)
  u16* qe   = (u16*)(ws + 0);              // 98304x256 bf16
  u16* km   = (u16*)(ws + 50331648);       // 24576x256 bf16
  u16* VT   = km;                          // aliases km (dead after KV GEMM): 384*8*32*64
  u16* QG   = (u16*)(ws + 62914560);       // 98304x512 bf16 (q | gate)
  u16* h1   = QG;                          // aliases QG (dead after attention)
  u16* KV   = (u16*)(ws + 163577856);      // 24576x512 bf16 (k | v)
  u16* O    = (u16*)(ws + 188743680);      // 98304x256 bf16 gated attn out
  u16* WQGT = (u16*)(ws + 239075328);      // [512][256]
  u16* WKVT = WQGT + 131072;               // [512][256]
  u16* WOUTT= WKVT + 131072;               // [256][256]
  u16* W1T  = WOUTT + 65536;               // [512][256]
  u16* W2T  = W1T + 131072;                // [256][512]
  u16* lnx  = qe;                          // aliases qe (dead after QG GEMM)

  convw_kernel<<<dim3(512, 6), 256, 0, stream>>>(Wq, Wg, Wkv, Wo, W1, W2,
      WQGT, WQGT + 65536, WKVT, WOUTT, W1T, W2T);
  ln_kernel<<<24576, 256, 0, stream>>>(embed, lnqs, lnqb, qe);
  ln_kernel<<<6144, 256, 0, stream>>>(memory, lnks, lnkb, km);
  // QG = qe @ [Wq|Wgate]
  gemm_kernel<<<dim3(2, 768), 512, 0, stream>>>(qe, WQGT, 256, 512, QG, nullptr,
      nullptr, nullptr, nullptr, 0, nullptr, nullptr, nullptr);
  // KV = km @ Wkv
  gemm_kernel<<<dim3(2, 192), 512, 0, stream>>>(km, WKVT, 256, 512, KV, nullptr,
      nullptr, nullptr, nullptr, 0, nullptr, nullptr, nullptr);
  vtrans_kernel<<<dim3(384, 8), 256, 0, stream>>>(KV, VT);
  attn_kernel<<<dim3(384, 16), 256, 0, stream>>>(QG, KV, VT, O);
  // out = embed + (O @ Wout)*rmask, plus FUSED LayerNorm -> lnx (bf16)
  gemm_kernel<<<dim3(1, 768), 512, 0, stream>>>(O, WOUTT, 256, 256, nullptr, out,
      nullptr, embed, rmask, 2, lnfs, lnfb, lnx);
  // h1 = relu(lnx @ W1 + b1)
  gemm_kernel<<<dim3(2, 768), 512, 0, stream>>>(lnx, W1T, 256, 512, h1, nullptr,
      b1, nullptr, nullptr, 1, nullptr, nullptr, nullptr);
  // out += (h1 @ W2 + b2)*rmask
  gemm_kernel<<<dim3(1, 768), 512, 0, stream>>>(h1, W2T, 512, 256, nullptr, out,
      b2, nullptr, rmask, 3, nullptr, nullptr, nullptr);
}